// Round 1
// baseline (44.438 us; speedup 1.0000x reference)
//
#include <hip/hip_runtime.h>

// PositionalEncoder: out[b,s,d] = x[b,s,d] + pe[s,d]
//   pe[s,d] = sin(s * 10000^{-d/D}) if d even else cos(...)
// B=4, S=8192, D=1024, fp32. Memory-bound: 256 MiB traffic -> ~42us floor.
// One thread owns one (s, d0..d0+3) float4 slot of the PE table, computes
// the 4 trig values ONCE, then loops over the 4 batch images (amortizes
// trig 4x). Manual range reduction to revolutions keeps v_sin_f32 in-domain.

constexpr int B = 4;
constexpr int S = 8192;
constexpr int D = 1024;

__global__ __launch_bounds__(256) void pe_add_kernel(
    const float* __restrict__ x, float* __restrict__ out) {
    const int tid = blockIdx.x * blockDim.x + threadIdx.x;   // over S*D/4
    const int dv  = tid & (D / 4 - 1);                       // which float4 in the row
    const int s   = tid >> 8;                                // D/4 = 256 slots per row
    const int d0  = dv * 4;

    const float LOG2_10000 = 13.28771237954945f;   // log2(10000)
    const float INV_2PI    = 0.15915494309189535f; // 1/(2*pi)
    const float TWO_PI     = 6.283185307179586f;

    const float fs = (float)s;
    float pe[4];
#pragma unroll
    for (int j = 0; j < 4; ++j) {
        const int d = d0 + j;
        // inv_freq = 10000^{-d/D} = 2^{-(d/D)*log2(10000)}  (one v_exp_f32)
        const float invf  = __builtin_exp2f(-((float)d * (1.0f / (float)D)) * LOG2_10000);
        const float angle = fs * invf;                // up to ~8191 rad at d=0
        float t = angle * INV_2PI;                    // revolutions
        t -= floorf(t);                               // fract -> [0,1)
        const float a = t * TWO_PI;                   // in [0, 2*pi): safe for HW sin/cos
        pe[j] = (j & 1) ? __cosf(a) : __sinf(a);     // even d -> sin, odd d -> cos
    }

    const float4 p4 = make_float4(pe[0], pe[1], pe[2], pe[3]);
    const size_t base = (size_t)s * D + d0;
#pragma unroll
    for (int b = 0; b < B; ++b) {
        const size_t off = (size_t)b * S * D + base;
        const float4 xv = *reinterpret_cast<const float4*>(x + off);
        float4 o;
        o.x = xv.x + p4.x;
        o.y = xv.y + p4.y;
        o.z = xv.z + p4.z;
        o.w = xv.w + p4.w;
        *reinterpret_cast<float4*>(out + off) = o;
    }
}

extern "C" void kernel_launch(void* const* d_in, const int* in_sizes, int n_in,
                              void* d_out, int out_size, void* d_ws, size_t ws_size,
                              hipStream_t stream) {
    const float* x = (const float*)d_in[0];
    float* out = (float*)d_out;
    const int threads = 256;
    const int total = S * D / 4;            // one thread per float4 of the PE table
    const int blocks = total / threads;     // 8192
    pe_add_kernel<<<blocks, threads, 0, stream>>>(x, out);
}